// Round 8
// baseline (207.088 us; speedup 1.0000x reference)
//
#include <hip/hip_runtime.h>
#include <math.h>

// LCAHeavyParentLoss: scalar = mean over [B,C] of BCE-with-logits(outputs,targets)
// + greedy-path parent cascade. B=2048, C=11110 (branching=10, depth=4).
//
// result = ( SUM_{B,C} [softplus(x) - x*t] + SUM_rows cascade ) / (B*C)
//
// R8: A/B vs R6 — identical contiguous-chunk structure, NT removed.
// R6 (contig+NT) = ~57us; R2-R4/R7 = 71us floor. Inputs are half-L3-resident
// (FETCH=90MB of 182MB demand); NT bypasses L3 allocation, possibly forfeiting
// concurrent L3 service. Single-variable test: plain global loads.

#define BRANCH 10
#define DEPTH  4
#define C_COLS 11110
#define NBLK   1024
#define NTHR   256

typedef float vfloat4 __attribute__((ext_vector_type(4)));

__device__ __forceinline__ float softplus_fast(float x) {
    // softplus(x) = max(x,0) + ln2 * log2(1 + exp2(-|x|*log2e))
    float ax = __builtin_fabsf(x);
    float p  = __builtin_amdgcn_exp2f(-1.44269504f * ax);   // v_exp_f32
    float l  = __builtin_amdgcn_logf(1.0f + p);             // v_log_f32
    return __builtin_fmaxf(x, 0.0f) + 0.69314718f * l;
}

__device__ __forceinline__ float bce4(vfloat4 xv, vfloat4 tv) {
    float a = softplus_fast(xv.x) - xv.x * tv.x;
    float b = softplus_fast(xv.y) - xv.y * tv.y;
    float c = softplus_fast(xv.z) - xv.z * tv.z;
    float d = softplus_fast(xv.w) - xv.w * tv.w;
    return (a + b) + (c + d);
}

__global__ __launch_bounds__(NTHR) void bce_path_kernel(
    const float* __restrict__ x, const float* __restrict__ t,
    float* __restrict__ partials, int n4, int n_rows)
{
    const vfloat4* __restrict__ x4 = (const vfloat4*)x;
    const vfloat4* __restrict__ t4 = (const vfloat4*)t;

    const int gtid = blockIdx.x * blockDim.x + threadIdx.x;

    float s0 = 0.0f, s1 = 0.0f, s2 = 0.0f, s3 = 0.0f;

    // --- path cascade: one row per global thread (first n_rows threads) ---
    if (gtid < n_rows) {
        const float* xr = x + (size_t)gtid * C_COLS;
        const float* tr = t + (size_t)gtid * C_COLS;
        int   e[DEPTH];
        float xv[DEPTH];
        int node = 0;
        #pragma unroll
        for (int l = 0; l < DEPTH; ++l) {
            int base = node * BRANCH;
            float best = xr[base];
            int   bi   = 0;
            #pragma unroll
            for (int c = 1; c < BRANCH; ++c) {
                float v = xr[base + c];
                if (v > best) { best = v; bi = c; }   // first-max, matches jnp.argmax
            }
            e[l]  = base + bi;
            xv[l] = best;
            node  = e[l] + 1;
        }
        float carry = 0.0f;
        #pragma unroll
        for (int l = DEPTH - 1; l >= 1; --l) {
            float addl = (tr[e[l]] == 0.0f) ? (softplus_fast(xv[l]) + carry) : 0.0f;
            s0   += addl;
            carry = addl;
        }
    }

    // --- main BCE sum: contiguous chunk per block, sequential streaming ---
    const int chunk = n4 / NBLK;                  // 5555 exactly
    const int start = blockIdx.x * chunk;
    const int end   = start + chunk;

    int p = start + threadIdx.x;
    // 5 full iterations for every thread (5120 of 5555 covered)
    for (; p + 3 * NTHR < end; p += 4 * NTHR) {
        vfloat4 a0 = x4[p];
        vfloat4 a1 = x4[p +     NTHR];
        vfloat4 a2 = x4[p + 2 * NTHR];
        vfloat4 a3 = x4[p + 3 * NTHR];
        vfloat4 b0 = t4[p];
        vfloat4 b1 = t4[p +     NTHR];
        vfloat4 b2 = t4[p + 2 * NTHR];
        vfloat4 b3 = t4[p + 3 * NTHR];
        s0 += bce4(a0, b0);
        s1 += bce4(a1, b1);
        s2 += bce4(a2, b2);
        s3 += bce4(a3, b3);
    }
    // masked tail (435 of 5555)
    for (; p < end; p += NTHR) {
        vfloat4 a = x4[p];
        vfloat4 b = t4[p];
        s0 += bce4(a, b);
    }
    float s = (s0 + s1) + (s2 + s3);

    // wave64 reduce
    #pragma unroll
    for (int off = 32; off > 0; off >>= 1)
        s += __shfl_down(s, off, 64);
    __shared__ float wsum[NTHR / 64];
    int lane = threadIdx.x & 63;
    int wid  = threadIdx.x >> 6;
    if (lane == 0) wsum[wid] = s;
    __syncthreads();
    if (threadIdx.x == 0)
        partials[blockIdx.x] = (wsum[0] + wsum[1]) + (wsum[2] + wsum[3]);
}

__global__ __launch_bounds__(NTHR) void final_reduce_kernel(
    const float* __restrict__ partials, float* __restrict__ out, float inv_scale)
{
    const vfloat4* p4 = (const vfloat4*)partials;   // NBLK/4 float4
    float s = 0.0f;
    for (int i = threadIdx.x; i < NBLK / 4; i += NTHR) {
        vfloat4 v = p4[i];
        s += (v.x + v.y) + (v.z + v.w);
    }
    #pragma unroll
    for (int off = 32; off > 0; off >>= 1)
        s += __shfl_down(s, off, 64);
    __shared__ float wsum[NTHR / 64];
    int lane = threadIdx.x & 63;
    int wid  = threadIdx.x >> 6;
    if (lane == 0) wsum[wid] = s;
    __syncthreads();
    if (threadIdx.x == 0)
        out[0] = ((wsum[0] + wsum[1]) + (wsum[2] + wsum[3])) * inv_scale;
}

extern "C" void kernel_launch(void* const* d_in, const int* in_sizes, int n_in,
                              void* d_out, int out_size, void* d_ws, size_t ws_size,
                              hipStream_t stream) {
    const float* outputs = (const float*)d_in[0];
    const float* targets = (const float*)d_in[1];
    float* out      = (float*)d_out;
    float* partials = (float*)d_ws;               // NBLK floats

    const int total = in_sizes[0];                // B * C = 22,753,280
    const int B     = total / C_COLS;             // 2048
    const int n4    = total / 4;                  // 5,688,320 = 1024 * 5555
    const float inv = 1.0f / (float)total;

    bce_path_kernel<<<NBLK, NTHR, 0, stream>>>(outputs, targets, partials, n4, B);
    final_reduce_kernel<<<1, NTHR, 0, stream>>>(partials, out, inv);
}

// Round 9
// 191.868 us; speedup vs baseline: 1.0793x; 1.0793x over previous
//
#include <hip/hip_runtime.h>
#include <math.h>

// LCAHeavyParentLoss: scalar = mean over [B,C] of BCE-with-logits(outputs,targets)
// + greedy-path parent cascade. B=2048, C=11110 (branching=10, depth=4).
//
// result = ( SUM_{B,C} [softplus(x) - x*t] + SUM_rows cascade ) / (B*C)
//
// R9: A/B established NT (no-allocate) is the active ingredient
// (contig+NT=57us vs contig=75us vs floor=71us). Now force true MLP on the
// NT path: compiler kept re-serializing to ~2-4 outstanding loads (VGPR
// 20/28/36); here 8 volatile inline-asm global_load_dwordx4 nt with
// explicitly live results + a waitcnt asm that owns the results.

#define BRANCH 10
#define DEPTH  4
#define C_COLS 11110
#define NBLK   1024
#define NTHR   256

typedef float vfloat4 __attribute__((ext_vector_type(4)));

__device__ __forceinline__ float softplus_fast(float x) {
    // softplus(x) = max(x,0) + ln2 * log2(1 + exp2(-|x|*log2e))
    float ax = __builtin_fabsf(x);
    float p  = __builtin_amdgcn_exp2f(-1.44269504f * ax);   // v_exp_f32
    float l  = __builtin_amdgcn_logf(1.0f + p);             // v_log_f32
    return __builtin_fmaxf(x, 0.0f) + 0.69314718f * l;
}

__device__ __forceinline__ vfloat4 ldnt4(const vfloat4* p) {
    return __builtin_nontemporal_load(p);
}

__device__ __forceinline__ float bce4(vfloat4 xv, vfloat4 tv) {
    float a = softplus_fast(xv.x) - xv.x * tv.x;
    float b = softplus_fast(xv.y) - xv.y * tv.y;
    float c = softplus_fast(xv.z) - xv.z * tv.z;
    float d = softplus_fast(xv.w) - xv.w * tv.w;
    return (a + b) + (c + d);
}

#define NT_LOAD(dst, addr) \
    asm volatile("global_load_dwordx4 %0, %1, off nt" : "=v"(dst) : "v"(addr))

__global__ __launch_bounds__(NTHR) void bce_path_kernel(
    const float* __restrict__ x, const float* __restrict__ t,
    float* __restrict__ partials, int n4, int n_rows)
{
    const vfloat4* __restrict__ x4 = (const vfloat4*)x;
    const vfloat4* __restrict__ t4 = (const vfloat4*)t;

    const int gtid = blockIdx.x * blockDim.x + threadIdx.x;

    float s0 = 0.0f, s1 = 0.0f, s2 = 0.0f, s3 = 0.0f;

    // --- path cascade: one row per global thread (first n_rows threads) ---
    if (gtid < n_rows) {
        const float* xr = x + (size_t)gtid * C_COLS;
        const float* tr = t + (size_t)gtid * C_COLS;
        int   e[DEPTH];
        float xv[DEPTH];
        int node = 0;
        #pragma unroll
        for (int l = 0; l < DEPTH; ++l) {
            int base = node * BRANCH;
            float best = xr[base];
            int   bi   = 0;
            #pragma unroll
            for (int c = 1; c < BRANCH; ++c) {
                float v = xr[base + c];
                if (v > best) { best = v; bi = c; }   // first-max, matches jnp.argmax
            }
            e[l]  = base + bi;
            xv[l] = best;
            node  = e[l] + 1;
        }
        float carry = 0.0f;
        #pragma unroll
        for (int l = DEPTH - 1; l >= 1; --l) {
            float addl = (tr[e[l]] == 0.0f) ? (softplus_fast(xv[l]) + carry) : 0.0f;
            s0   += addl;
            carry = addl;
        }
    }

    // --- main BCE sum: contiguous chunk/block, forced 8-deep NT loads ---
    const int chunk = n4 / NBLK;                  // 5555 exactly
    const int start = blockIdx.x * chunk;
    const int end   = start + chunk;

    int p = start + threadIdx.x;
    for (; p + 3 * NTHR < end; p += 4 * NTHR) {
        vfloat4 a0, a1, a2, a3, b0, b1, b2, b3;
        NT_LOAD(a0, x4 + p);
        NT_LOAD(a1, x4 + p +     NTHR);
        NT_LOAD(a2, x4 + p + 2 * NTHR);
        NT_LOAD(a3, x4 + p + 3 * NTHR);
        NT_LOAD(b0, t4 + p);
        NT_LOAD(b1, t4 + p +     NTHR);
        NT_LOAD(b2, t4 + p + 2 * NTHR);
        NT_LOAD(b3, t4 + p + 3 * NTHR);
        // wait owns the results: uses below cannot be hoisted above it
        asm volatile("s_waitcnt vmcnt(0)"
                     : "+v"(a0), "+v"(a1), "+v"(a2), "+v"(a3),
                       "+v"(b0), "+v"(b1), "+v"(b2), "+v"(b3)
                     :: "memory");
        s0 += bce4(a0, b0);
        s1 += bce4(a1, b1);
        s2 += bce4(a2, b2);
        s3 += bce4(a3, b3);
    }
    // masked tail (435 of 5555)
    for (; p < end; p += NTHR) {
        vfloat4 a = ldnt4(&x4[p]);
        vfloat4 b = ldnt4(&t4[p]);
        s0 += bce4(a, b);
    }
    float s = (s0 + s1) + (s2 + s3);

    // wave64 reduce
    #pragma unroll
    for (int off = 32; off > 0; off >>= 1)
        s += __shfl_down(s, off, 64);
    __shared__ float wsum[NTHR / 64];
    int lane = threadIdx.x & 63;
    int wid  = threadIdx.x >> 6;
    if (lane == 0) wsum[wid] = s;
    __syncthreads();
    if (threadIdx.x == 0)
        partials[blockIdx.x] = (wsum[0] + wsum[1]) + (wsum[2] + wsum[3]);
}

__global__ __launch_bounds__(NTHR) void final_reduce_kernel(
    const float* __restrict__ partials, float* __restrict__ out, float inv_scale)
{
    const vfloat4* p4 = (const vfloat4*)partials;   // NBLK/4 float4
    float s = 0.0f;
    for (int i = threadIdx.x; i < NBLK / 4; i += NTHR) {
        vfloat4 v = p4[i];
        s += (v.x + v.y) + (v.z + v.w);
    }
    #pragma unroll
    for (int off = 32; off > 0; off >>= 1)
        s += __shfl_down(s, off, 64);
    __shared__ float wsum[NTHR / 64];
    int lane = threadIdx.x & 63;
    int wid  = threadIdx.x >> 6;
    if (lane == 0) wsum[wid] = s;
    __syncthreads();
    if (threadIdx.x == 0)
        out[0] = ((wsum[0] + wsum[1]) + (wsum[2] + wsum[3])) * inv_scale;
}

extern "C" void kernel_launch(void* const* d_in, const int* in_sizes, int n_in,
                              void* d_out, int out_size, void* d_ws, size_t ws_size,
                              hipStream_t stream) {
    const float* outputs = (const float*)d_in[0];
    const float* targets = (const float*)d_in[1];
    float* out      = (float*)d_out;
    float* partials = (float*)d_ws;               // NBLK floats

    const int total = in_sizes[0];                // B * C = 22,753,280
    const int B     = total / C_COLS;             // 2048
    const int n4    = total / 4;                  // 5,688,320 = 1024 * 5555
    const float inv = 1.0f / (float)total;

    bce_path_kernel<<<NBLK, NTHR, 0, stream>>>(outputs, targets, partials, n4, B);
    final_reduce_kernel<<<1, NTHR, 0, stream>>>(partials, out, inv);
}

// Round 10
// 189.055 us; speedup vs baseline: 1.0954x; 1.0149x over previous
//
#include <hip/hip_runtime.h>
#include <math.h>

// LCAHeavyParentLoss: scalar = mean over [B,C] of BCE-with-logits(outputs,targets)
// + greedy-path parent cascade. B=2048, C=11110 (branching=10, depth=4).
//
// result = ( SUM_{B,C} [softplus(x) - x*t] + SUM_rows cascade ) / (B*C)
//
// R10: last lever on the NT path — grid-level miss parallelism.
// R6/R9 (contig+NT, 1024 blocks = 50% occ cap) both hit 3.2 TB/s; forced
// 8-deep per-wave MLP changed nothing. Test 2560 blocks (10/CU, up to 100%
// occupancy, chunk = n4/2560 = 2222 float4 exactly). If invariant, ~3.2 TB/s
// is the read-return ceiling and we are at the roofline.

#define BRANCH 10
#define DEPTH  4
#define C_COLS 11110
#define NBLK   2560
#define NTHR   256

typedef float vfloat4 __attribute__((ext_vector_type(4)));

__device__ __forceinline__ float softplus_fast(float x) {
    // softplus(x) = max(x,0) + ln2 * log2(1 + exp2(-|x|*log2e))
    float ax = __builtin_fabsf(x);
    float p  = __builtin_amdgcn_exp2f(-1.44269504f * ax);   // v_exp_f32
    float l  = __builtin_amdgcn_logf(1.0f + p);             // v_log_f32
    return __builtin_fmaxf(x, 0.0f) + 0.69314718f * l;
}

__device__ __forceinline__ vfloat4 ldnt4(const vfloat4* p) {
    return __builtin_nontemporal_load(p);
}

__device__ __forceinline__ float bce4(vfloat4 xv, vfloat4 tv) {
    float a = softplus_fast(xv.x) - xv.x * tv.x;
    float b = softplus_fast(xv.y) - xv.y * tv.y;
    float c = softplus_fast(xv.z) - xv.z * tv.z;
    float d = softplus_fast(xv.w) - xv.w * tv.w;
    return (a + b) + (c + d);
}

__global__ __launch_bounds__(NTHR) void bce_path_kernel(
    const float* __restrict__ x, const float* __restrict__ t,
    float* __restrict__ partials, int n4, int n_rows)
{
    const vfloat4* __restrict__ x4 = (const vfloat4*)x;
    const vfloat4* __restrict__ t4 = (const vfloat4*)t;

    const int gtid = blockIdx.x * blockDim.x + threadIdx.x;

    float s0 = 0.0f, s1 = 0.0f, s2 = 0.0f, s3 = 0.0f;

    // --- path cascade: one row per global thread (first n_rows threads) ---
    if (gtid < n_rows) {
        const float* xr = x + (size_t)gtid * C_COLS;
        const float* tr = t + (size_t)gtid * C_COLS;
        int   e[DEPTH];
        float xv[DEPTH];
        int node = 0;
        #pragma unroll
        for (int l = 0; l < DEPTH; ++l) {
            int base = node * BRANCH;
            float best = xr[base];
            int   bi   = 0;
            #pragma unroll
            for (int c = 1; c < BRANCH; ++c) {
                float v = xr[base + c];
                if (v > best) { best = v; bi = c; }   // first-max, matches jnp.argmax
            }
            e[l]  = base + bi;
            xv[l] = best;
            node  = e[l] + 1;
        }
        float carry = 0.0f;
        #pragma unroll
        for (int l = DEPTH - 1; l >= 1; --l) {
            float addl = (tr[e[l]] == 0.0f) ? (softplus_fast(xv[l]) + carry) : 0.0f;
            s0   += addl;
            carry = addl;
        }
    }

    // --- main BCE sum: contiguous chunk per block, NT streaming ---
    const int chunk = n4 / NBLK;                  // 2222 exactly
    const int start = blockIdx.x * chunk;
    const int end   = start + chunk;

    int p = start + threadIdx.x;
    // 2 full unrolled iterations (2048 of 2222)
    for (; p + 3 * NTHR < end; p += 4 * NTHR) {
        vfloat4 a0 = ldnt4(&x4[p]);
        vfloat4 a1 = ldnt4(&x4[p +     NTHR]);
        vfloat4 a2 = ldnt4(&x4[p + 2 * NTHR]);
        vfloat4 a3 = ldnt4(&x4[p + 3 * NTHR]);
        vfloat4 b0 = ldnt4(&t4[p]);
        vfloat4 b1 = ldnt4(&t4[p +     NTHR]);
        vfloat4 b2 = ldnt4(&t4[p + 2 * NTHR]);
        vfloat4 b3 = ldnt4(&t4[p + 3 * NTHR]);
        s0 += bce4(a0, b0);
        s1 += bce4(a1, b1);
        s2 += bce4(a2, b2);
        s3 += bce4(a3, b3);
    }
    // masked tail (174 of 2222)
    for (; p < end; p += NTHR) {
        vfloat4 a = ldnt4(&x4[p]);
        vfloat4 b = ldnt4(&t4[p]);
        s0 += bce4(a, b);
    }
    float s = (s0 + s1) + (s2 + s3);

    // wave64 reduce
    #pragma unroll
    for (int off = 32; off > 0; off >>= 1)
        s += __shfl_down(s, off, 64);
    __shared__ float wsum[NTHR / 64];
    int lane = threadIdx.x & 63;
    int wid  = threadIdx.x >> 6;
    if (lane == 0) wsum[wid] = s;
    __syncthreads();
    if (threadIdx.x == 0)
        partials[blockIdx.x] = (wsum[0] + wsum[1]) + (wsum[2] + wsum[3]);
}

__global__ __launch_bounds__(NTHR) void final_reduce_kernel(
    const float* __restrict__ partials, float* __restrict__ out, float inv_scale)
{
    const vfloat4* p4 = (const vfloat4*)partials;   // NBLK/4 = 640 float4
    float s = 0.0f;
    for (int i = threadIdx.x; i < NBLK / 4; i += NTHR) {
        vfloat4 v = p4[i];
        s += (v.x + v.y) + (v.z + v.w);
    }
    #pragma unroll
    for (int off = 32; off > 0; off >>= 1)
        s += __shfl_down(s, off, 64);
    __shared__ float wsum[NTHR / 64];
    int lane = threadIdx.x & 63;
    int wid  = threadIdx.x >> 6;
    if (lane == 0) wsum[wid] = s;
    __syncthreads();
    if (threadIdx.x == 0)
        out[0] = ((wsum[0] + wsum[1]) + (wsum[2] + wsum[3])) * inv_scale;
}

extern "C" void kernel_launch(void* const* d_in, const int* in_sizes, int n_in,
                              void* d_out, int out_size, void* d_ws, size_t ws_size,
                              hipStream_t stream) {
    const float* outputs = (const float*)d_in[0];
    const float* targets = (const float*)d_in[1];
    float* out      = (float*)d_out;
    float* partials = (float*)d_ws;               // NBLK floats

    const int total = in_sizes[0];                // B * C = 22,753,280
    const int B     = total / C_COLS;             // 2048
    const int n4    = total / 4;                  // 5,688,320 = 2560 * 2222
    const float inv = 1.0f / (float)total;

    bce_path_kernel<<<NBLK, NTHR, 0, stream>>>(outputs, targets, partials, n4, B);
    final_reduce_kernel<<<1, NTHR, 0, stream>>>(partials, out, inv);
}